// Round 1
// baseline (286.854 us; speedup 1.0000x reference)
//
#include <hip/hip_runtime.h>

#define IMG  1024
#define TILE 64
#define HALO 5
#define LW   (TILE + 2 * HALO)   // 74
#define NEG_INF (-__builtin_inff())

__global__ __launch_bounds__(256)
void simple_nms_kernel(const float* __restrict__ in, float* __restrict__ out) {
    __shared__ float         sc[LW][LW];
    __shared__ unsigned char mk[LW][LW];
    __shared__ unsigned char sp[LW][LW];

    const int tid = threadIdx.x;
    const int x0  = (int)blockIdx.x * TILE - HALO;
    const int y0  = (int)blockIdx.y * TILE - HALO;
    const size_t base = (size_t)blockIdx.z * IMG * IMG;

    // ---- load scores tile (+halo-5); OOB = -inf (emulates SAME clipped window) ----
    for (int i = tid; i < LW * LW; i += 256) {
        int r = i / LW, c = i - r * LW;
        int gy = y0 + r, gx = x0 + c;
        float v = NEG_INF;
        if ((unsigned)gy < (unsigned)IMG && (unsigned)gx < (unsigned)IMG)
            v = in[base + (size_t)gy * IMG + gx];
        sc[r][c] = v;
    }
    __syncthreads();

    // ---- m0 = (s == maxpool3(s)) on rows/cols [1, 73) ----
    {
        const int n = LW - 2;  // 72
        for (int i = tid; i < n * n; i += 256) {
            int r = i / n + 1, c = (i % n) + 1;
            float v  = sc[r][c];
            float mx = v;
            mx = fmaxf(mx, sc[r-1][c-1]); mx = fmaxf(mx, sc[r-1][c]); mx = fmaxf(mx, sc[r-1][c+1]);
            mx = fmaxf(mx, sc[r  ][c-1]);                             mx = fmaxf(mx, sc[r  ][c+1]);
            mx = fmaxf(mx, sc[r+1][c-1]); mx = fmaxf(mx, sc[r+1][c]); mx = fmaxf(mx, sc[r+1][c+1]);
            mk[r][c] = (v == mx) ? (unsigned char)1 : (unsigned char)0;
        }
    }
    __syncthreads();

#pragma unroll
    for (int k = 0; k < 2; ++k) {
        // supp = maxpool3(mask) > 0   on [os, LW-os)
        const int os = 2 + 2 * k;
        const int ns = LW - 2 * os;  // 70, 66
        for (int i = tid; i < ns * ns; i += 256) {
            int r = i / ns + os, c = (i % ns) + os;
            unsigned a = (unsigned)mk[r-1][c-1] | mk[r-1][c] | mk[r-1][c+1]
                       | mk[r  ][c-1] | mk[r  ][c] | mk[r  ][c+1]
                       | mk[r+1][c-1] | mk[r+1][c] | mk[r+1][c+1];
            sp[r][c] = (unsigned char)a;
        }
        __syncthreads();

        // new_max = (ss == maxpool3(ss)); mask |= new_max & ~supp   on [on, LW-on)
        const int on = os + 1;
        const int nn = LW - 2 * on;  // 68, 64
        for (int i = tid; i < nn * nn; i += 256) {
            int r = i / nn + on, c = (i % nn) + on;

            auto ssv = [&](int rr, int cc) -> float {
                float b = sc[rr][cc];
                // suppressed in-image -> 0; OOB stays -inf (clipped-window exact)
                return (sp[rr][cc] && b != NEG_INF) ? 0.f : b;
            };

            unsigned spc = sp[r][c];
            float vc  = sc[r][c];
            float ssc = (spc && vc != NEG_INF) ? 0.f : vc;
            float mx  = ssc;
            mx = fmaxf(mx, ssv(r-1, c-1)); mx = fmaxf(mx, ssv(r-1, c)); mx = fmaxf(mx, ssv(r-1, c+1));
            mx = fmaxf(mx, ssv(r,   c-1));                              mx = fmaxf(mx, ssv(r,   c+1));
            mx = fmaxf(mx, ssv(r+1, c-1)); mx = fmaxf(mx, ssv(r+1, c)); mx = fmaxf(mx, ssv(r+1, c+1));

            unsigned nm = (ssc == mx) ? 1u : 0u;
            mk[r][c] = (unsigned char)(mk[r][c] | (nm & (spc ^ 1u)));
        }
        __syncthreads();
    }

    // ---- out = mask ? scores : 0  on the central 64x64 ----
    for (int i = tid; i < TILE * TILE; i += 256) {
        int r = i / TILE + HALO, c = (i % TILE) + HALO;
        int gy = y0 + r, gx = x0 + c;
        out[base + (size_t)gy * IMG + gx] = mk[r][c] ? sc[r][c] : 0.f;
    }
}

extern "C" void kernel_launch(void* const* d_in, const int* in_sizes, int n_in,
                              void* d_out, int out_size, void* d_ws, size_t ws_size,
                              hipStream_t stream) {
    const float* in = (const float*)d_in[0];
    float* out = (float*)d_out;
    const int batch = in_sizes[0] / (IMG * IMG);
    dim3 grid(IMG / TILE, IMG / TILE, batch);
    simple_nms_kernel<<<grid, dim3(256, 1, 1), 0, stream>>>(in, out);
}

// Round 4
// 154.346 us; speedup vs baseline: 1.8585x; 1.8585x over previous
//
#include <hip/hip_runtime.h>

#define IMG   1024
#define TILE  64
#define LW    74          // tile rows/cols incl. halo 5
#define PITCH 88          // floats per LDS row: 4 left-pad + 74 + right pad (16B-aligned stride)
#define NEG_INF (-__builtin_inff())

// One stencil pass: for rows [r0, r0+nrows), col units of 8, compute
// m = (ss == maxpool3(ss)) [& ~supp], OR bits into mkw. USE_SP=false => ss = sc (m0 pass).
template<bool USE_SP>
__device__ __forceinline__ void stencil_pass(const float (&sc)[LW][PITCH],
                                             const unsigned (&spw)[LW][3],
                                             unsigned (&mkw)[LW][3],
                                             int tid, int r0, int nrows, int c0, int c1)
{
    const int NU = 10;  // 8-px units per row (cols 0..79)
    for (int u = tid; u < nrows * NU; u += 256) {
        const int r = u / NU + r0;
        const int b = (u - (u / NU) * NU) * 8;   // base tile-col of this unit

        float vm[16];      // vertical max over 3 rows of (supp-masked) scores, cols b-4..b+11
        float cs[8];       // center-row ss values, cols b..b+7
        unsigned cw = 0;   // center-row supp bits, cols b..b+7

#pragma unroll
        for (int dr = 0; dr < 3; ++dr) {
            const int rr = r - 1 + dr;

            unsigned win = 0;  // supp bits: win bit i <-> tile col (b-4)+i
            if (USE_SP) {
                if (b == 0) {
                    win = spw[rr][0] << 4;           // cols <0 -> 0
                } else {
                    const int s = b - 4, q = s >> 5, sh = s & 31;  // sh in {4,12,20,28}
                    const unsigned lo = spw[rr][q];
                    const unsigned hi = (q < 2) ? spw[rr][q + 1] : 0u;
                    win = (lo >> sh) | (hi << (32 - sh));
                }
            }

            const float* row = &sc[rr][b];   // LDS idx b <-> tile col b-4; 16B aligned (b%8==0)
            const float4 f0 = *(const float4*)(row);
            const float4 f1 = *(const float4*)(row + 4);
            const float4 f2 = *(const float4*)(row + 8);
            const float4 f3 = *(const float4*)(row + 12);
            float f[16] = { f0.x, f0.y, f0.z, f0.w,  f1.x, f1.y, f1.z, f1.w,
                            f2.x, f2.y, f2.z, f2.w,  f3.x, f3.y, f3.z, f3.w };

#pragma unroll
            for (int i = 0; i < 16; ++i) {
                float v = f[i];
                if (USE_SP) {
                    if (((win >> i) & 1u) && v != NEG_INF) v = 0.f;  // suppressed real px -> 0
                }
                f[i] = v;
            }
            if (dr == 1) {
#pragma unroll
                for (int j = 0; j < 8; ++j) cs[j] = f[4 + j];
                cw = win >> 4;
            }
#pragma unroll
            for (int i = 0; i < 16; ++i) vm[i] = dr ? fmaxf(vm[i], f[i]) : f[i];
        }

        unsigned bits = 0;
#pragma unroll
        for (int j = 0; j < 8; ++j) {
            const float mx = fmaxf(fmaxf(vm[3 + j], vm[4 + j]), vm[5 + j]);
            const float v = cs[j];
            bool ok = (v == mx) && (v != NEG_INF);   // real px only (exact clipped-window match)
            if (USE_SP) ok = ok && !((cw >> j) & 1u);  // & ~supp
            const int col = b + j;
            ok = ok && (col >= c0) && (col <= c1);
            bits |= ok ? (1u << ((b & 31) + j)) : 0u;
        }
        if (bits) atomicOr(&mkw[r][b >> 5], bits);
    }
}

__global__ __launch_bounds__(256)
void simple_nms_kernel(const float* __restrict__ in, float* __restrict__ out)
{
    __shared__ float    sc[LW][PITCH];
    __shared__ unsigned mk[LW][3];   // max_mask, bitpacked: col c -> word c>>5, bit c&31
    __shared__ unsigned sp[LW][3];   // supp mask
    __shared__ unsigned hb[LW][3];   // horizontal-OR scratch

    const int tid = threadIdx.x;
    const int x0 = (int)blockIdx.x * TILE - 5;
    const int y0 = (int)blockIdx.y * TILE - 5;
    const size_t base = (size_t)blockIdx.z * ((size_t)IMG * IMG);

    for (int i = tid; i < LW * 3; i += 256) { mk[i / 3][i % 3] = 0u; sp[i / 3][i % 3] = 0u; }

    // ---- load scores (+halo); OOB = -inf (exact clipped-window emulation) ----
    for (int i = tid; i < LW * PITCH; i += 256) {
        const int r = i / PITCH, c = i - r * PITCH;
        const int gy = y0 + r, gx = x0 + (c - 4);
        float v = NEG_INF;
        if ((unsigned)gy < (unsigned)IMG && (unsigned)gx < (unsigned)IMG)
            v = in[base + (size_t)gy * IMG + gx];
        sc[r][c] = v;
    }
    __syncthreads();

    // ---- m0 on [1..72]^2 ----
    stencil_pass<false>(sc, sp, mk, tid, 1, 72, 1, 72);
    __syncthreads();

    for (int k = 0; k < 2; ++k) {
        // ---- supp = maxpool3(mask) — bitwise, separable ----
        for (int i = tid; i < LW * 3; i += 256) {
            const int r = i / 3, w = i - r * 3;
            const unsigned m  = mk[r][w];
            const unsigned l  = w ? mk[r][w - 1] : 0u;
            const unsigned rt = (w < 2) ? mk[r][w + 1] : 0u;
            hb[r][w] = m | (m << 1) | (l >> 31) | (m >> 1) | (rt << 31);
        }
        __syncthreads();
        for (int i = tid; i < LW * 3; i += 256) {
            const int r = i / 3, w = i - r * 3;
            unsigned a = hb[r][w];
            if (r > 0)      a |= hb[r - 1][w];
            if (r < LW - 1) a |= hb[r + 1][w];
            sp[r][w] = a;
        }
        __syncthreads();

        // ---- mask |= (ss == maxpool3(ss)) & ~supp ----
        if (k == 0) stencil_pass<true>(sc, sp, mk, tid, 3, 68, 3, 70);
        else        stencil_pass<true>(sc, sp, mk, tid, 5, 64, 5, 68);
        __syncthreads();
    }

    // ---- out = mask ? scores : 0 on the central 64x64 ----
    for (int i = tid; i < TILE * TILE; i += 256) {
        const int r = (i >> 6) + 5, c = (i & 63) + 5;
        const unsigned bit = (mk[r][c >> 5] >> (c & 31)) & 1u;
        const float v = bit ? sc[r][c + 4] : 0.f;
        out[base + (size_t)(y0 + r) * IMG + (x0 + c)] = v;
    }
}

extern "C" void kernel_launch(void* const* d_in, const int* in_sizes, int n_in,
                              void* d_out, int out_size, void* d_ws, size_t ws_size,
                              hipStream_t stream) {
    const float* in = (const float*)d_in[0];
    float* out = (float*)d_out;
    const int batch = in_sizes[0] / (IMG * IMG);
    dim3 grid(IMG / TILE, IMG / TILE, batch);
    simple_nms_kernel<<<grid, dim3(256, 1, 1), 0, stream>>>(in, out);
}

// Round 6
// 60.855 us; speedup vs baseline: 4.7137x; 2.5363x over previous
//
#include <hip/hip_runtime.h>

#define IMG 1024
#define RH  32               // output rows per band
#define NW  4                // waves per block (256 threads, 4 cols/lane = 1024 cols)
#define NEG_INF (-__builtin_inff())
#define PMASK 0x01010101u    // bit0 of each byte = current-row bit plane, byte i = col i of lane

__device__ __forceinline__ float max3f(float a, float b, float c) {
    return fmaxf(fmaxf(a, b), c);
}

__device__ __forceinline__ float4 vmax3(float4 a, float4 b, float4 c) {
    return make_float4(max3f(a.x,b.x,c.x), max3f(a.y,b.y,c.y),
                       max3f(a.z,b.z,c.z), max3f(a.w,b.w,c.w));
}

// horizontal 3-max across the 4 cols of this lane + neighbor edge values
__device__ __forceinline__ float4 hmax3(float4 f, float Lin, float Rin, int lane) {
    float sl = __shfl(f.w, lane - 1);     // left lane's col3 (wraps for lane0 — overridden)
    float sr = __shfl(f.x, lane + 1);     // right lane's col0
    float L = (lane == 0)  ? Lin : sl;
    float R = (lane == 63) ? Rin : sr;
    return make_float4(max3f(L,   f.x, f.y),
                       max3f(f.x, f.y, f.z),
                       max3f(f.y, f.z, f.w),
                       max3f(f.z, f.w, R));
}

// horizontal 3-OR on a byte-per-col bit plane
__device__ __forceinline__ unsigned hor3(unsigned p, unsigned Lbit, unsigned Rbit, int lane) {
    unsigned sl = (unsigned)__shfl((int)p, lane - 1);
    unsigned sr = (unsigned)__shfl((int)p, lane + 1);
    unsigned L = (lane == 0)  ? Lbit : ((sl >> 24) & 1u);
    unsigned R = (lane == 63) ? Rbit : (sr & 1u);
    return ((p | (p << 8) | (p >> 8)) & PMASK) | L | (R << 24);
}

// plane bit = (a == m) && (vv != -inf)   [vv!=-inf: real-pixel guard, exact clipped-window]
__device__ __forceinline__ unsigned cmp_plane(float4 a, float4 m, float4 vv) {
    unsigned r = 0;
    r |= (a.x == m.x && vv.x != NEG_INF) ? 1u : 0u;
    r |= (a.y == m.y && vv.y != NEG_INF) ? 0x100u : 0u;
    r |= (a.z == m.z && vv.z != NEG_INF) ? 0x10000u : 0u;
    r |= (a.w == m.w && vv.w != NEG_INF) ? 0x1000000u : 0u;
    return r;
}

// suppressed real px -> 0; OOB (-inf) stays -inf
__device__ __forceinline__ float4 supsel(unsigned plane, float4 vv) {
    return make_float4(
        ((plane & 1u)         && vv.x != NEG_INF) ? 0.f : vv.x,
        ((plane & 0x100u)     && vv.y != NEG_INF) ? 0.f : vv.y,
        ((plane & 0x10000u)   && vv.z != NEG_INF) ? 0.f : vv.z,
        ((plane & 0x1000000u) && vv.w != NEG_INF) ? 0.f : vv.w);
}

__global__ __launch_bounds__(256)
void nms_sweep(const float* __restrict__ in, float* __restrict__ out)
{
    // edge packets: {v, ss1, ss2, bits(m0|mask1<<1)}; [parity][wave+1], slots 0 / NW+1 = sentinels
    __shared__ float4 edgeR[2][NW + 2];  // lane63 col3 values of each wave
    __shared__ float4 edgeL[2][NW + 2];  // lane0  col0 values of each wave

    const int tid  = threadIdx.x;
    const int lane = tid & 63;
    const int w    = tid >> 6;
    const int y0   = (int)blockIdx.x * RH;
    const int yend = y0 + RH;
    const size_t base = (size_t)blockIdx.y * ((size_t)IMG * IMG);
    const int col0 = tid * 4;
    const int lmax = (yend + 5 < IMG) ? yend + 5 : IMG;  // rows >= yend+5 never affect this band

    // init ALL edge slots (both parities) to sentinel {-inf,-inf,-inf,bits=0}
    for (int i = tid; i < 2 * 2 * (NW + 2); i += 256) {
        int p = i & 1, sl = (i >> 1) % (NW + 2), side = i / (2 * (NW + 2));
        float4 s = make_float4(NEG_INF, NEG_INF, NEG_INF, __uint_as_float(0u));
        if (side) edgeR[p][sl] = s; else edgeL[p][sl] = s;
    }

    auto loadrow = [&](int r) -> float4 {
        if (r >= 0 && r < lmax)
            return *(const float4*)&in[base + (size_t)r * IMG + col0];
        return make_float4(NEG_INF, NEG_INF, NEG_INF, NEG_INF);
    };

    // pipeline state (v[j] = scores row s-j after insert)
    float4 v[11];
    float4 hv0, hv1, hv2;     // hmax(v) rows s-1, s-2, s-3
    float4 h1a, h1b, h1c;     // hmax(ss1) rows s-5, s-6, s-7
    float4 h2a, h2b, h2c;     // hmax(ss2) rows s-9, s-10, s-11
    float4 ss1p, ss2p;        // ss1 row s-4, ss2 row s-8 (from previous step)
    unsigned m0h = 0, hm0h = 0, s1h = 0, mk1h = 0, hm1h = 0, s2h = 0;  // bit histories

    const float4 ninf4 = make_float4(NEG_INF, NEG_INF, NEG_INF, NEG_INF);
#pragma unroll
    for (int j = 0; j < 11; ++j) v[j] = ninf4;
    hv0 = hv1 = hv2 = h1a = h1b = h1c = h2a = h2b = h2c = ninf4;
    ss1p = ss2p = ninf4;

    const int s_begin = y0 - 5;
    const int s_last  = y0 + RH + 9;
    float4 pend1 = loadrow(s_begin);
    float4 pend2 = loadrow(s_begin + 1);
    __syncthreads();  // edge-slot init visible

    for (int s = s_begin; s <= s_last; ++s) {
        const int par = s & 1, pp = par ^ 1;

        // insert row s; prefetch row s+2
#pragma unroll
        for (int j = 10; j >= 1; --j) v[j] = v[j - 1];
        v[0] = pend1;
        pend1 = pend2;
        pend2 = loadrow(s + 2);

        // previous step's edge packets (uniform per wave -> LDS broadcast)
        const float4 pL = edgeR[pp][w];          // left wave's right-edge packet
        const float4 pR = edgeL[pp][w + 2];      // right wave's left-edge packet
        const unsigned pLb = __float_as_uint(pL.w);
        const unsigned pRb = __float_as_uint(pR.w);

        // S3: hv for row s-1
        hv2 = hv1; hv1 = hv0;
        hv0 = hmax3(v[1], pL.x, pR.x, lane);

        // S4: m0 for row s-2
        float4 vm0 = vmax3(hv0, hv1, hv2);
        unsigned m0n = cmp_plane(v[2], vm0, v[2]);
        m0h = ((m0h << 1) & ~PMASK) | m0n;

        // S5: hm0 for row s-3
        unsigned m0l1 = (m0h >> 1) & PMASK;
        unsigned hm0n = hor3(m0l1, pLb & 1u, pRb & 1u, lane);
        hm0h = ((hm0h << 1) & ~PMASK) | hm0n;

        // S6: supp1 for row s-4 (vertical OR of hm0 rows s-3..s-5)
        unsigned s1n = (hm0h | (hm0h >> 1) | (hm0h >> 2)) & PMASK;
        s1h = ((s1h << 1) & ~PMASK) | s1n;

        // S7: ss1 for row s-4
        float4 ss1n = supsel(s1n, v[4]);

        // S8: h1 for row s-5
        h1c = h1b; h1b = h1a;
        h1a = hmax3(ss1p, pL.y, pR.y, lane);
        ss1p = ss1n;

        // S9: nm1, mask1 for row s-6
        float4 vm1 = vmax3(h1a, h1b, h1c);
        unsigned s1l2 = (s1h >> 2) & PMASK;
        float4 ss1_6 = supsel(s1l2, v[6]);
        unsigned nm1 = cmp_plane(ss1_6, vm1, v[6]);
        unsigned m0l4 = (m0h >> 4) & PMASK;
        unsigned mk1n = m0l4 | (nm1 & ~s1l2 & PMASK);
        mk1h = ((mk1h << 1) & ~PMASK) | mk1n;

        // S10: hm1 for row s-7
        unsigned mk1l1 = (mk1h >> 1) & PMASK;
        unsigned hm1n = hor3(mk1l1, (pLb >> 1) & 1u, (pRb >> 1) & 1u, lane);
        hm1h = ((hm1h << 1) & ~PMASK) | hm1n;

        // S11: supp2 for row s-8
        unsigned s2n = (hm1h | (hm1h >> 1) | (hm1h >> 2)) & PMASK;
        s2h = ((s2h << 1) & ~PMASK) | s2n;

        // S12: ss2 for row s-8
        float4 ss2n = supsel(s2n, v[8]);

        // S13: h2 for row s-9
        h2c = h2b; h2b = h2a;
        h2a = hmax3(ss2p, pL.z, pR.z, lane);
        ss2p = ss2n;

        // S14: mask2 + output for row s-10
        float4 vm2 = vmax3(h2a, h2b, h2c);
        unsigned s2l2 = (s2h >> 2) & PMASK;
        float4 ss2_10 = supsel(s2l2, v[10]);
        unsigned nm2 = cmp_plane(ss2_10, vm2, v[10]);
        unsigned mk1l4 = (mk1h >> 4) & PMASK;
        unsigned mk2 = mk1l4 | (nm2 & ~s2l2 & PMASK);
        const int srow = s - 10;
        if (srow >= y0 && srow < yend) {
            float4 o = make_float4(
                (mk2 & 1u)         ? v[10].x : 0.f,
                (mk2 & 0x100u)     ? v[10].y : 0.f,
                (mk2 & 0x10000u)   ? v[10].z : 0.f,
                (mk2 & 0x1000000u) ? v[10].w : 0.f);
            *(float4*)&out[base + (size_t)srow * IMG + col0] = o;
        }

        // write this step's edge packets (consumed next step)
        unsigned bitsR = ((m0n >> 24) & 1u) | (((mk1n >> 24) & 1u) << 1);
        unsigned bitsL = (m0n & 1u) | ((mk1n & 1u) << 1);
        if (lane == 63) edgeR[par][w + 1] = make_float4(v[0].w, ss1n.w, ss2n.w, __uint_as_float(bitsR));
        if (lane == 0)  edgeL[par][w + 1] = make_float4(v[0].x, ss1n.x, ss2n.x, __uint_as_float(bitsL));
        __syncthreads();
    }
}

extern "C" void kernel_launch(void* const* d_in, const int* in_sizes, int n_in,
                              void* d_out, int out_size, void* d_ws, size_t ws_size,
                              hipStream_t stream) {
    const float* in = (const float*)d_in[0];
    float* out = (float*)d_out;
    const int batch = in_sizes[0] / (IMG * IMG);
    dim3 grid(IMG / RH, batch, 1);
    nms_sweep<<<grid, dim3(256, 1, 1), 0, stream>>>(in, out);
}

// Round 7
// 44.873 us; speedup vs baseline: 6.3925x; 1.3562x over previous
//
#include <hip/hip_runtime.h>

#define IMG 1024
#define RH  32               // output rows per band
#define NW  4                // waves per block (256 threads, 4 cols/lane = 1024 cols)
#define NEG_INF (-__builtin_inff())
#define PMASK 0x01010101u    // bit0 of each byte = current-row bit plane, byte i = col i of lane

// ---- DPP lane+-1 exchange (wave_shr:1 = 0x138, wave_shl:1 = 0x130; gfx9-lineage) ----
__device__ __forceinline__ unsigned dpp_shr1_u(unsigned x) {   // lane i <- lane i-1 (lane0 -> 0)
    return (unsigned)__builtin_amdgcn_update_dpp(0, (int)x, 0x138, 0xf, 0xf, true);
}
__device__ __forceinline__ unsigned dpp_shl1_u(unsigned x) {   // lane i <- lane i+1 (lane63 -> 0)
    return (unsigned)__builtin_amdgcn_update_dpp(0, (int)x, 0x130, 0xf, 0xf, true);
}
__device__ __forceinline__ float dpp_shr1_f(float x) { return __uint_as_float(dpp_shr1_u(__float_as_uint(x))); }
__device__ __forceinline__ float dpp_shl1_f(float x) { return __uint_as_float(dpp_shl1_u(__float_as_uint(x))); }

__device__ __forceinline__ float max3f(float a, float b, float c) { return fmaxf(fmaxf(a, b), c); }

__device__ __forceinline__ float4 vmax3(float4 a, float4 b, float4 c) {
    return make_float4(max3f(a.x,b.x,c.x), max3f(a.y,b.y,c.y),
                       max3f(a.z,b.z,c.z), max3f(a.w,b.w,c.w));
}

__device__ __forceinline__ float4 hmax3(float4 f, float Lin, float Rin, bool l0, bool l63) {
    float sl = dpp_shr1_f(f.w);
    float sr = dpp_shl1_f(f.x);
    float L = l0 ? Lin : sl;
    float R = l63 ? Rin : sr;
    return make_float4(max3f(L,   f.x, f.y), max3f(f.x, f.y, f.z),
                       max3f(f.y, f.z, f.w), max3f(f.z, f.w, R));
}

__device__ __forceinline__ unsigned hor3(unsigned p, unsigned Lbit, unsigned Rbit, bool l0, bool l63) {
    unsigned sl = dpp_shr1_u(p);
    unsigned sr = dpp_shl1_u(p);
    unsigned L = l0 ? Lbit : ((sl >> 24) & 1u);
    unsigned R = l63 ? Rbit : (sr & 1u);
    return ((p | (p << 8) | (p >> 8)) & PMASK) | L | (R << 24);
}

// equality plane, unguarded (row-validity applied by scalar rvm AND outside)
__device__ __forceinline__ unsigned cmp_plane(float4 a, float4 m) {
    return (a.x == m.x ? 0x1u : 0u) | (a.y == m.y ? 0x100u : 0u) |
           (a.z == m.z ? 0x10000u : 0u) | (a.w == m.w ? 0x1000000u : 0u);
}

// plane already AND'd with row-validity: bit set -> real suppressed pixel -> 0
__device__ __forceinline__ float4 supsel(unsigned plane, float4 v) {
    return make_float4(((plane >>  0) & 1u) ? 0.f : v.x,
                       ((plane >>  8) & 1u) ? 0.f : v.y,
                       ((plane >> 16) & 1u) ? 0.f : v.z,
                       ((plane >> 24) & 1u) ? 0.f : v.w);
}

__device__ __forceinline__ float bsel(unsigned bits, int sh, float v) {
    return ((bits >> sh) & 1u) ? v : 0.f;
}

// scalar (wave-uniform) per-row validity mask
__device__ __forceinline__ unsigned vmask(int r, int lmax) {
    return ((unsigned)r < (unsigned)lmax) ? PMASK : 0u;
}

// One pipeline step; K = 0..3 within unrolled group, PAR = (sb+K)&1 (compile-time).
#define STEP(K, PAR) do {                                                               \
    const int s_ = sb + (K);                                                            \
    const float4 pLp = edgeR[(PAR)^1][w];                                               \
    const float4 pRp = edgeL[(PAR)^1][w + 2];                                           \
    const unsigned pLb = __float_as_uint(pLp.w);                                        \
    const unsigned pRb = __float_as_uint(pRp.w);                                        \
    /* S3: hmax(scores) row s-1 */                                                      \
    HV[(K)+2] = hmax3(H[9+(K)], pLp.x, pRp.x, l0, l63);                                 \
    /* S4: m0 row s-2 */                                                                \
    float4 vm0 = vmax3(HV[(K)+2], HV[(K)+1], HV[(K)]);                                  \
    unsigned m0n = cmp_plane(H[8+(K)], vm0) & vmask(s_ - 2, lmax);                      \
    m0h = ((m0h << 1) & ~PMASK) | m0n;                                                  \
    /* S5: hm0 row s-3 */                                                               \
    unsigned hm0n = hor3((m0h >> 1) & PMASK, pLb & 1u, pRb & 1u, l0, l63);              \
    hm0h = ((hm0h << 1) & ~PMASK) | hm0n;                                               \
    /* S6: supp1 row s-4 */                                                             \
    unsigned s1n = (hm0h | (hm0h >> 1) | (hm0h >> 2)) & PMASK;                          \
    s1h = ((s1h << 1) & ~PMASK) | s1n;                                                  \
    /* S7: ss1 row s-4 */                                                               \
    SS1[(K)+1] = supsel(s1n & vmask(s_ - 4, lmax), H[6+(K)]);                           \
    /* S8: hmax(ss1) row s-5 */                                                         \
    H1[(K)+2] = hmax3(SS1[(K)], pLp.y, pRp.y, l0, l63);                                 \
    /* S9: mask1 row s-6 */                                                             \
    float4 vm1 = vmax3(H1[(K)+2], H1[(K)+1], H1[(K)]);                                  \
    unsigned s1l2 = (s1h >> 2) & PMASK;                                                 \
    unsigned rvm6 = vmask(s_ - 6, lmax);                                                \
    float4 ss16 = supsel(s1l2 & rvm6, H[4+(K)]);                                        \
    unsigned nm1 = cmp_plane(ss16, vm1) & rvm6;                                         \
    unsigned mk1n = ((m0h >> 4) & PMASK) | (nm1 & ~s1l2);                               \
    mk1h = ((mk1h << 1) & ~PMASK) | mk1n;                                               \
    /* S10: hm1 row s-7 */                                                              \
    unsigned hm1n = hor3((mk1h >> 1) & PMASK, (pLb >> 1) & 1u, (pRb >> 1) & 1u, l0, l63);\
    hm1h = ((hm1h << 1) & ~PMASK) | hm1n;                                               \
    /* S11: supp2 row s-8 */                                                            \
    unsigned s2n = (hm1h | (hm1h >> 1) | (hm1h >> 2)) & PMASK;                          \
    s2h = ((s2h << 1) & ~PMASK) | s2n;                                                  \
    /* S12: ss2 row s-8 */                                                              \
    SS2[(K)+1] = supsel(s2n & vmask(s_ - 8, lmax), H[2+(K)]);                           \
    /* S13: hmax(ss2) row s-9 */                                                        \
    H2[(K)+2] = hmax3(SS2[(K)], pLp.z, pRp.z, l0, l63);                                 \
    /* S14: mask2 + output row s-10 */                                                  \
    float4 vm2 = vmax3(H2[(K)+2], H2[(K)+1], H2[(K)]);                                  \
    unsigned s2l2 = (s2h >> 2) & PMASK;                                                 \
    unsigned rvm10 = vmask(s_ - 10, lmax);                                              \
    float4 ss210 = supsel(s2l2 & rvm10, H[(K)]);                                        \
    unsigned nm2 = cmp_plane(ss210, vm2) & rvm10;                                       \
    unsigned mk2 = ((mk1h >> 4) & PMASK) | (nm2 & ~s2l2);                               \
    const int srow = s_ - 10;                                                           \
    if (srow >= y0 && srow < yend) {                                                    \
        float4 vv = H[(K)];                                                             \
        outp4[(size_t)srow * (IMG/4) + tid] = make_float4(                              \
            bsel(mk2, 0, vv.x), bsel(mk2, 8, vv.y),                                     \
            bsel(mk2, 16, vv.z), bsel(mk2, 24, vv.w));                                  \
    }                                                                                   \
    unsigned bitsR = ((m0n >> 24) & 1u) | (((mk1n >> 24) & 1u) << 1);                   \
    unsigned bitsL = (m0n & 1u) | ((mk1n & 1u) << 1);                                   \
    if (l63) edgeR[(PAR)][w + 1] = make_float4(H[10+(K)].w, SS1[(K)+1].w, SS2[(K)+1].w, __uint_as_float(bitsR)); \
    if (l0)  edgeL[(PAR)][w + 1] = make_float4(H[10+(K)].x, SS1[(K)+1].x, SS2[(K)+1].x, __uint_as_float(bitsL)); \
    __syncthreads();                                                                    \
} while (0)

__global__ __launch_bounds__(256, 2)
void nms_sweep(const float* __restrict__ in, float* __restrict__ out)
{
    __shared__ float4 edgeR[2][NW + 2];
    __shared__ float4 edgeL[2][NW + 2];

    const int tid  = threadIdx.x;
    const int lane = tid & 63;
    const int w    = tid >> 6;
    const bool l0  = (lane == 0);
    const bool l63 = (lane == 63);
    const int y0   = (int)blockIdx.x * RH;
    const int yend = y0 + RH;
    const size_t base = (size_t)blockIdx.y * ((size_t)IMG * IMG);
    const int lmax = (yend + 5 < IMG) ? yend + 5 : IMG;

    const float4* inp4  = (const float4*)(in + base);
    float4*       outp4 = (float4*)(out + base);

    // init edge slots (both parities) to sentinel {-inf,-inf,-inf,bits=0}
    for (int i = tid; i < 2 * (NW + 2); i += 256) {
        int p = i & 1, sl = i >> 1;
        float4 s = make_float4(NEG_INF, NEG_INF, NEG_INF, __uint_as_float(0u));
        edgeR[p][sl] = s;
        edgeL[p][sl] = s;
    }

    const float4 ninf4 = make_float4(NEG_INF, NEG_INF, NEG_INF, NEG_INF);
    // H[i]  = scores row sb-10+i          (carried i=0..9, loaded i=10..13)
    // HV[i] = hmax(scores) row sb-3+i     (carried i=0,1)
    // SS1[i]= ss1 row sb-5+i              (carried i=0)
    // H1[i] = hmax(ss1) row sb-7+i        (carried i=0,1)
    // SS2[i]= ss2 row sb-9+i              (carried i=0)
    // H2[i] = hmax(ss2) row sb-11+i       (carried i=0,1)
    float4 H[14], HV[6], SS1[5], H1[6], SS2[5], H2[6];
#pragma unroll
    for (int i = 0; i < 14; ++i) H[i] = ninf4;
#pragma unroll
    for (int i = 0; i < 6; ++i) { HV[i] = ninf4; H1[i] = ninf4; H2[i] = ninf4; }
#pragma unroll
    for (int i = 0; i < 5; ++i) { SS1[i] = ninf4; SS2[i] = ninf4; }
    unsigned m0h = 0, hm0h = 0, s1h = 0, mk1h = 0, hm1h = 0, s2h = 0;

    __syncthreads();

    int sb = y0 - 5;   // y0 even -> sb odd -> PAR sequence per group: 1,0,1,0 (static)
    for (int it = 0; it < 12; ++it) {
        // load this group's 4 rows (first use is one step later -> latency hidden)
#pragma unroll
        for (int k = 0; k < 4; ++k) {
            const int r = sb + k;
            if ((unsigned)r < (unsigned)lmax) H[10 + k] = inp4[(size_t)r * (IMG/4) + tid];
            else                              H[10 + k] = ninf4;
        }

        STEP(0, 1);
        STEP(1, 0);
        STEP(2, 1);
        STEP(3, 0);

        // rotate state by 4 rows (static indices -> pure register renames/movs)
#pragma unroll
        for (int i = 0; i < 10; ++i) H[i] = H[i + 4];
        HV[0] = HV[4];  HV[1] = HV[5];
        SS1[0] = SS1[4];
        H1[0] = H1[4];  H1[1] = H1[5];
        SS2[0] = SS2[4];
        H2[0] = H2[4];  H2[1] = H2[5];
        sb += 4;
    }
}

extern "C" void kernel_launch(void* const* d_in, const int* in_sizes, int n_in,
                              void* d_out, int out_size, void* d_ws, size_t ws_size,
                              hipStream_t stream) {
    const float* in = (const float*)d_in[0];
    float* out = (float*)d_out;
    const int batch = in_sizes[0] / (IMG * IMG);
    dim3 grid(IMG / RH, batch, 1);
    nms_sweep<<<grid, dim3(256, 1, 1), 0, stream>>>(in, out);
}